// Round 11
// baseline (2031.051 us; speedup 1.0000x reference)
//
#include <hip/hip_runtime.h>
#include <hip/hip_fp16.h>

// Problem constants
#define BATCH 8
#define NPTS 1500         // N
#define DIM 256           // D
#define M1 1501           // NPTS+1 (couplings dim)
#define KH 1536           // padded row stride for fp16 K matrix (24*64 halves)
#define MROWS 24000       // 2*B*N rows through the MLP
#define ITERS 50
#define MU_PT (1.0f / 3000.0f)
#define MU_BIN 0.5f
#define NBB 64            // blocks per batch (grid = 8*NBB = 512)

typedef _Float16 half8 __attribute__((ext_vector_type(8)));
typedef float f32x4 __attribute__((ext_vector_type(4)));

__device__ __forceinline__ float4 ld4(const float* p){ return *(const float4*)p; }

// Agent-scope (coherence-point / L2-bypassing) atomic helpers: all cross-block
// Sinkhorn state goes through these, so NO cache fences are ever needed.
__device__ __forceinline__ float aload(const float* p) {
  return __hip_atomic_load(p, __ATOMIC_RELAXED, __HIP_MEMORY_SCOPE_AGENT);
}
__device__ __forceinline__ void aadd(float* p, float v) {
  (void)__hip_atomic_fetch_add(p, v, __ATOMIC_RELAXED, __HIP_MEMORY_SCOPE_AGENT);
}
__device__ __forceinline__ void azero(float* p) {
  (void)__hip_atomic_exchange(p, 0.f, __ATOMIC_RELAXED, __HIP_MEMORY_SCOPE_AGENT);
}

// ---------------------------------------------------------------------------
// prep: Wt[n][k] = fp16(W[k][n]) for W1 (512x256), W2, W3 (256x256).
// ---------------------------------------------------------------------------
__global__ void prep_w_kernel(const float* __restrict__ W1, const float* __restrict__ W2,
                              const float* __restrict__ W3, __half* __restrict__ Wt1,
                              __half* __restrict__ Wt2, __half* __restrict__ Wt3)
{
  int gid = blockIdx.x * 256 + threadIdx.x;
  if (gid < 512 * 256) {
    int n = gid >> 9, k = gid & 511;
    Wt1[gid] = __float2half(W1[k * 256 + n]);
  } else if (gid < 512 * 256 + 256 * 256) {
    int g = gid - 512 * 256; int n = g >> 8, k = g & 255;
    Wt2[g] = __float2half(W2[k * 256 + n]);
  } else if (gid < 512 * 256 + 2 * 256 * 256) {
    int g = gid - 512 * 256 - 256 * 256; int n = g >> 8, k = g & 255;
    Wt3[g] = __float2half(W3[k * 256 + n]);
  }
}

// ---------------------------------------------------------------------------
// MFMA fp16 GEMM, 128x128x32 tiles, 4 waves x (4x4 of 16x16x32 MFMA).
// (unchanged, harness-verified)
// ---------------------------------------------------------------------------
template<int MODE>
__global__ __launch_bounds__(256) void mfma_gemm_kernel(
    const float* __restrict__ Aq, const float* __restrict__ Ap_end,
    const float* __restrict__ Ap_start, const __half* __restrict__ Ah,
    const __half* __restrict__ Bh, const float* __restrict__ bias,
    __half* __restrict__ out)
{
  const int K = (MODE == 0) ? 512 : 256;
  const int M = (MODE == 3) ? NPTS : MROWS;
  __shared__ _Float16 As[128][40];
  __shared__ _Float16 Bs[128][40];
  const int t = threadIdx.x;
  const int lane = t & 63;
  const int wave = t >> 6;
  const int quad = lane >> 4, l15 = lane & 15;
  const int wm = wave & 1, wn = wave >> 1;
  const int m0 = blockIdx.x * 128;
  const int n0 = blockIdx.y * 128;
  const int b  = (MODE == 3) ? blockIdx.z : 0;
  const __half* F1 = Ah + (size_t)b * NPTS * 256;
  const __half* F2 = Ah + (size_t)(12000 + b * NPTS) * 256;

  f32x4 acc[4][4];
#pragma unroll
  for (int i = 0; i < 4; ++i)
#pragma unroll
    for (int j = 0; j < 4; ++j) acc[i][j] = (f32x4){0.f, 0.f, 0.f, 0.f};

  const int sr = t >> 1;            // staging row 0..127
  const int c0 = (t & 1) * 16;      // staging col offset {0,16}

  for (int kt = 0; kt < K; kt += 32) {
    // ---- stage A tile (128 x 32 halves) ----
    {
      int grow = m0 + sr;
      if (MODE == 0) {
        union { half8 v[2]; _Float16 s[16]; } U;
        if (grow < M) {
          int col = kt + c0;
          int r12 = (grow < 12000) ? grow : grow - 12000;
          const float* src;
          if (col < 256) src = Aq + (size_t)r12 * 256 + col;
          else src = ((grow < 12000) ? Ap_end : Ap_start) + (size_t)r12 * 256 + (col - 256);
#pragma unroll
          for (int i = 0; i < 4; ++i) {
            float4 w = ld4(src + 4 * i);
            U.s[4*i+0] = (_Float16)w.x; U.s[4*i+1] = (_Float16)w.y;
            U.s[4*i+2] = (_Float16)w.z; U.s[4*i+3] = (_Float16)w.w;
          }
        } else {
#pragma unroll
          for (int i = 0; i < 16; ++i) U.s[i] = (_Float16)0.f;
        }
        *(half8*)&As[sr][c0]     = U.v[0];
        *(half8*)&As[sr][c0 + 8] = U.v[1];
      } else {
        const __half* src = ((MODE == 3) ? F1 : Ah) + (size_t)grow * 256 + kt + c0;
        uint4 u0 = make_uint4(0,0,0,0), u1 = make_uint4(0,0,0,0);
        if (grow < M) { u0 = *(const uint4*)src; u1 = *(const uint4*)(src + 8); }
        *(uint4*)&As[sr][c0]     = u0;
        *(uint4*)&As[sr][c0 + 8] = u1;
      }
    }
    // ---- stage B tile (128 n-rows x 32 k) ----
    {
      int n = n0 + sr;
      uint4 u0 = make_uint4(0,0,0,0), u1 = make_uint4(0,0,0,0);
      if (MODE == 3) {
        if (n < NPTS) {
          const __half* src = F2 + (size_t)n * 256 + kt + c0;
          u0 = *(const uint4*)src; u1 = *(const uint4*)(src + 8);
        }
      } else {
        const __half* src = Bh + (size_t)n * K + kt + c0;
        u0 = *(const uint4*)src; u1 = *(const uint4*)(src + 8);
      }
      *(uint4*)&Bs[sr][c0]     = u0;
      *(uint4*)&Bs[sr][c0 + 8] = u1;
    }
    __syncthreads();
    // ---- MFMA ----
    half8 af[4], bf[4];
#pragma unroll
    for (int sm = 0; sm < 4; ++sm)
      af[sm] = *(half8*)&As[wm * 64 + sm * 16 + l15][quad * 8];
#pragma unroll
    for (int sn = 0; sn < 4; ++sn)
      bf[sn] = *(half8*)&Bs[wn * 64 + sn * 16 + l15][quad * 8];
#pragma unroll
    for (int sm = 0; sm < 4; ++sm)
#pragma unroll
      for (int sn = 0; sn < 4; ++sn)
        acc[sm][sn] = __builtin_amdgcn_mfma_f32_16x16x32_f16(af[sm], bf[sn], acc[sm][sn], 0, 0, 0);
    __syncthreads();
  }

  // ---- epilogue ----
  if (MODE == 3) {
    __half* Kb = out + (size_t)b * M1 * KH;
#pragma unroll
    for (int sm = 0; sm < 4; ++sm) {
      int rbase = m0 + wm * 64 + sm * 16 + quad * 4;
#pragma unroll
      for (int reg = 0; reg < 4; ++reg) {
        int gi = rbase + reg;
        if (gi < NPTS) {
#pragma unroll
          for (int sn = 0; sn < 4; ++sn) {
            int gj = n0 + wn * 64 + sn * 16 + l15;
            float v = acc[sm][sn][reg] * 0.0625f;
            float kv = (gj < NPTS && gj != gi) ? __expf(v) : 0.f;
            Kb[(size_t)gi * KH + gj] = __float2half(kv);
          }
        }
      }
    }
  } else {
    float bv[4];
#pragma unroll
    for (int sn = 0; sn < 4; ++sn) bv[sn] = bias[n0 + wn * 64 + sn * 16 + l15];
#pragma unroll
    for (int sm = 0; sm < 4; ++sm) {
      int rbase = m0 + wm * 64 + sm * 16 + quad * 4;
#pragma unroll
      for (int reg = 0; reg < 4; ++reg) {
        int gr = rbase + reg;
        if (gr < MROWS) {
#pragma unroll
          for (int sn = 0; sn < 4; ++sn) {
            int col = n0 + wn * 64 + sn * 16 + l15;
            float v = acc[sm][sn][reg] + bv[sn];
            if (MODE != 2) v = fmaxf(v, 0.f);
            out[(size_t)gr * 256 + col] = __float2half(v);
          }
        }
      }
    }
  }
}

// ---------------------------------------------------------------------------
// bins: bin row/col = fp16(exp(alpha)); zero bin-row pads; zero csum0;
// zero per-batch barrier counters.
// ---------------------------------------------------------------------------
__global__ void bins_kernel(__half* __restrict__ Kh, const float* __restrict__ palpha,
                            float* __restrict__ csum0, unsigned* __restrict__ bar)
{
  int gid = blockIdx.x * 256 + threadIdx.x;
  if (gid >= BATCH * KH) return;
  if (gid < BATCH) bar[gid * 64] = 0u;   // counters one cacheline apart
  int b = gid / KH, x = gid % KH;
  __half He = __float2half(expf(palpha[0]));
  __half* Kb = Kh + (size_t)b * M1 * KH;
  csum0[gid] = 0.f;
  if (x < M1) {
    Kb[(size_t)NPTS * KH + x] = He;   // bin row
    Kb[(size_t)x * KH + NPTS] = He;   // bin col (corner included)
  } else {
    Kb[(size_t)NPTS * KH + x] = __float2half(0.f); // bin-row pads
  }
}

// ---------------------------------------------------------------------------
// Persistent fused Sinkhorn v2: ONE dispatch, 50 iterations + finalize.
//
// Differences vs the round-1 45us/iter version (whose cost was the
// __threadfence L2 writeback-invalidate pair, NOT the barrier concept):
//   * ALL cross-block state (csum reads, csum zeroing) uses agent-scope
//     atomics that execute at the coherence point (L3, sc1) and bypass L2
//     -> no cache maintenance instruction anywhere.
//   * Release ordering is free: __syncthreads() drains each wave's vmcnt
//     (compiler-emitted s_waitcnt vmcnt(0) before s_barrier), and the
//     csum atomicAdds are RETURNING agent-scope ops, so once drained they
//     are globally performed.  t==0 then signals the per-batch counter.
//   * Acquire is free: polling + subsequent csum reads are agent-scope
//     atomic loads (read from L3 directly; nothing stale to invalidate).
//
// K rows live in REGISTERS (18 x uint4/lane, loaded once, reused 50 iters
// + the fused finalize).  Co-residency by capacity: 128-VGPR-class body
// (round-0 measured), 6 KB LDS, __launch_bounds__(256,2) -> 2 blocks/CU,
// grid 512 = 2 x 256 CUs (empirically co-resident in round 1).
// ---------------------------------------------------------------------------
__global__ __launch_bounds__(256, 2) void sink_fused_kernel(
    const __half* __restrict__ Kh,
    float* __restrict__ c0, float* __restrict__ c1, float* __restrict__ c2,
    unsigned* __restrict__ bar, float* __restrict__ out)
{
  const int t = threadIdx.x;
  const int wave = t >> 6, lane = t & 63;
  const int bb = blockIdx.x & 7;   // batch == XCD (heuristic, perf-only)
  const int rb = blockIdx.x >> 3;  // block-in-batch, 0..63
  const int nrows = (rb < 29) ? 24 : 23;   // rows rb+64*s < M1
  const __half* Kb = Kh + (size_t)bb * M1 * KH;
  unsigned* mybar = bar + bb * 64;

  __shared__ float cpart[KH];      // transposed 4-wave combine buffer

  // ---- load this block's K rows into registers (once) ----
  uint4 kreg[6][3];
#pragma unroll
  for (int q = 0; q < 6; ++q) {
    int s = wave + (q << 2);
    if (s < nrows) {
      const __half* rp = Kb + (size_t)(rb + (s << 6)) * KH + (lane << 3);
#pragma unroll
      for (int k = 0; k < 3; ++k) kreg[q][k] = *(const uint4*)(rp + (k << 9));
    } else {
#pragma unroll
      for (int k = 0; k < 3; ++k) kreg[q][k] = make_uint4(0u, 0u, 0u, 0u);
    }
  }
  for (int j = t; j < KH; j += 256) cpart[j] = 0.f;
  __syncthreads();

  // csum roles: it=0 -> prev=c2 (unused), cur=c0 (zeroed by bins), next=c1
  float* cprev = c2;
  float* ccur  = c0;
  float* cnext = c1;

  float ev[24];
  float euk[6];

  for (int it = 0; it < ITERS; ++it) {
    // ---- phase A: per-lane ev at cols lane*8+j + k*512 (agent loads) ----
    if (it == 0) {
#pragma unroll
      for (int k = 0; k < 3; ++k) {
        int cbase = (lane << 3) + (k << 9);
#pragma unroll
        for (int j = 0; j < 8; ++j) ev[k * 8 + j] = (cbase + j < M1) ? 1.0f : 0.f;
      }
    } else {
      const float* cp = cprev + bb * KH;
#pragma unroll
      for (int k = 0; k < 3; ++k) {
        int cbase = (lane << 3) + (k << 9);
#pragma unroll
        for (int j = 0; j < 8; ++j) {
          int col = cbase + j;
          float cs = aload(cp + col);
          float nu = (col < NPTS) ? MU_PT : ((col == NPTS) ? MU_BIN : 0.f);
          ev[k * 8 + j] = (col < M1) ? (nu / cs) : 0.f;
        }
      }
    }
    // zero next-iteration csum slice (agent-scope; 24 cols per block)
    if (t < 24) azero(&cnext[bb * KH + rb * 24 + t]);

    // ---- phase B: rows (K from registers, ev from registers) ----
    float acc[24];
#pragma unroll
    for (int j = 0; j < 24; ++j) acc[j] = 0.f;
#pragma unroll
    for (int q = 0; q < 6; ++q) {
      int s = wave + (q << 2);
      if (s < nrows) {
        int row = rb + (s << 6);
        float r[24], dot = 0.f;
#pragma unroll
        for (int k = 0; k < 3; ++k) {
          union { uint4 u; __half2 h[4]; } U;
          U.u = kreg[q][k];
#pragma unroll
          for (int m = 0; m < 4; ++m) {
            float2 f = __half22float2(U.h[m]);
            r[k * 8 + 2 * m]     = f.x;
            r[k * 8 + 2 * m + 1] = f.y;
          }
          dot += r[k*8+0]*ev[k*8+0] + r[k*8+1]*ev[k*8+1] + r[k*8+2]*ev[k*8+2] + r[k*8+3]*ev[k*8+3]
               + r[k*8+4]*ev[k*8+4] + r[k*8+5]*ev[k*8+5] + r[k*8+6]*ev[k*8+6] + r[k*8+7]*ev[k*8+7];
        }
#pragma unroll
        for (int off = 32; off > 0; off >>= 1) dot += __shfl_xor(dot, off);
        float mu = (row < NPTS) ? MU_PT : MU_BIN;
        float euv = mu / dot;
        euk[q] = euv;
#pragma unroll
        for (int j = 0; j < 24; ++j) acc[j] += r[j] * euv;
      }
    }

    // ---- phase C: 4-wave combine in LDS (transposed, conflict-free) ----
#pragma unroll
    for (int k = 0; k < 3; ++k)
#pragma unroll
      for (int j = 0; j < 8; ++j)
        atomicAdd(&cpart[(((k << 3) + j) << 6) + lane], acc[k * 8 + j]);
    __syncthreads();

    // ---- phase D: one agent-scope atomic per column per block; re-zero ----
    {
      float* cc = ccur + bb * KH;
#pragma unroll
      for (int p = 0; p < 6; ++p) {
        int c = t + (p << 8);
        int kk = c >> 9, rem = c & 511;
        int idx = (((kk << 3) + (rem & 7)) << 6) + (rem >> 3);
        float v = cpart[idx];
        cpart[idx] = 0.f;
        if (c < M1) aadd(&cc[c], v);
      }
    }

    // ---- per-batch barrier: syncthreads drains all waves' vmcnt (release),
    //      then t==0 signals and polls agent-scope counter (no fences) ----
    __syncthreads();
    if (t == 0) {
      (void)__hip_atomic_fetch_add(mybar, 1u, __ATOMIC_RELAXED, __HIP_MEMORY_SCOPE_AGENT);
      unsigned tgt = (unsigned)NBB * (unsigned)(it + 1);
      while (__hip_atomic_load(mybar, __ATOMIC_RELAXED, __HIP_MEMORY_SCOPE_AGENT) < tgt)
        __builtin_amdgcn_s_sleep(2);
    }
    __syncthreads();

    // rotate csum roles
    float* tmp = cprev; cprev = ccur; ccur = cnext; cnext = tmp;
  }

  // ---- fused finalize: evf = nu/csum_last; out = K * eu * ev * 3000 ----
  float evf[24];
  {
    const float* cp = cprev + bb * KH;   // cprev == last iteration's csum
#pragma unroll
    for (int k = 0; k < 3; ++k) {
      int cbase = (lane << 3) + (k << 9);
#pragma unroll
      for (int j = 0; j < 8; ++j) {
        int col = cbase + j;
        float cs = aload(cp + col);
        float nu = (col < NPTS) ? MU_PT : ((col == NPTS) ? MU_BIN : 0.f);
        evf[k * 8 + j] = (col < M1) ? (nu / cs) : 0.f;
      }
    }
  }
#pragma unroll
  for (int q = 0; q < 6; ++q) {
    int s = wave + (q << 2);
    if (s < nrows) {
      int row = rb + (s << 6);
      float scale = euk[q] * 3000.0f;
      float* orow = out + ((size_t)bb * M1 + row) * M1;
#pragma unroll
      for (int k = 0; k < 3; ++k) {
        union { uint4 u; __half2 h[4]; } U;
        U.u = kreg[q][k];
        float f[8];
#pragma unroll
        for (int m = 0; m < 4; ++m) {
          float2 g = __half22float2(U.h[m]);
          f[2 * m] = g.x; f[2 * m + 1] = g.y;
        }
        int cb = (lane << 3) + (k << 9);
#pragma unroll
        for (int j = 0; j < 8; ++j) {
          int col = cb + j;
          if (col < M1) orow[col] = f[j] * evf[k * 8 + j] * scale;
        }
      }
    }
  }
}

// ---------------------------------------------------------------------------
extern "C" void kernel_launch(void* const* d_in, const int* in_sizes, int n_in,
                              void* d_out, int out_size, void* d_ws, size_t ws_size,
                              hipStream_t stream)
{
  const float* quer      = (const float*)d_in[0];
  const float* pos_start = (const float*)d_in[1];
  const float* pos_end   = (const float*)d_in[2];
  const float* W1 = (const float*)d_in[3];
  const float* b1 = (const float*)d_in[4];
  const float* W2 = (const float*)d_in[5];
  const float* b2 = (const float*)d_in[6];
  const float* W3 = (const float*)d_in[7];
  const float* b3 = (const float*)d_in[8];
  const float* alpha = (const float*)d_in[9];

  char* ws = (char*)d_ws;
  size_t off = 0;
  auto carve = [&](size_t bytes) -> void* {
    void* p = ws + off;
    off += (bytes + 1023) & ~(size_t)1023;
    return p;
  };
  __half* Ha  = (__half*)carve((size_t)MROWS * 256 * 2);          // 12.3 MB
  __half* Hb  = (__half*)carve((size_t)MROWS * 256 * 2);          // 12.3 MB
  __half* Kh  = (__half*)carve((size_t)BATCH * M1 * KH * 2);      // 36.9 MB
  __half* Wt1 = (__half*)carve((size_t)256 * 512 * 2);
  __half* Wt2 = (__half*)carve((size_t)256 * 256 * 2);
  __half* Wt3 = (__half*)carve((size_t)256 * 256 * 2);
  float* csum[3];
  for (int c = 0; c < 3; ++c) csum[c] = (float*)carve((size_t)BATCH * KH * 4);
  unsigned* bar = (unsigned*)carve((size_t)BATCH * 64 * sizeof(unsigned));
  (void)ws_size; (void)in_sizes; (void)n_in; (void)out_size;

  dim3 blk(256);
  // weight prep (fp16, transposed to [n][k])
  prep_w_kernel<<<dim3(1024), blk, 0, stream>>>(W1, W2, W3, Wt1, Wt2, Wt3);
  // MLP via MFMA: Ha = relu([q|p]W1+b1); Hb = relu(Ha W2+b2); Ha = Hb W3+b3
  mfma_gemm_kernel<0><<<dim3(188, 2), blk, 0, stream>>>(quer, pos_end, pos_start, nullptr, Wt1, b1, Ha);
  mfma_gemm_kernel<1><<<dim3(188, 2), blk, 0, stream>>>(nullptr, nullptr, nullptr, Ha, Wt2, b2, Hb);
  mfma_gemm_kernel<2><<<dim3(188, 2), blk, 0, stream>>>(nullptr, nullptr, nullptr, Hb, Wt3, b3, Ha);
  // scores -> Kh (fp16 exp domain, pads zeroed)
  mfma_gemm_kernel<3><<<dim3(12, 12, 8), blk, 0, stream>>>(nullptr, nullptr, nullptr, Ha, nullptr, nullptr, Kh);
  bins_kernel<<<dim3((BATCH * KH + 255) / 256), blk, 0, stream>>>(Kh, alpha, csum[0], bar);
  // persistent fused sinkhorn (50 iters) + finalize, ONE dispatch, no fences
  sink_fused_kernel<<<dim3(512), blk, 0, stream>>>(Kh, csum[0], csum[1], csum[2], bar, (float*)d_out);
}

// Round 12
// 644.344 us; speedup vs baseline: 3.1521x; 3.1521x over previous
//
#include <hip/hip_runtime.h>
#include <hip/hip_fp16.h>

// Problem constants
#define BATCH 8
#define NPTS 1500         // N
#define DIM 256           // D
#define M1 1501           // NPTS+1 (couplings dim)
#define KH 1536           // padded row stride for fp16 K matrix (24*64 halves)
#define MROWS 24000       // 2*B*N rows through the MLP
#define ITERS 50
#define MU_PT (1.0f / 3000.0f)
#define MU_BIN 0.5f

typedef _Float16 half8 __attribute__((ext_vector_type(8)));
typedef float f32x4 __attribute__((ext_vector_type(4)));
typedef unsigned int u32x4 __attribute__((ext_vector_type(4)));

__device__ __forceinline__ float4 ld4(const float* p){ return *(const float4*)p; }

// ---------------------------------------------------------------------------
// prep: Wt[n][k] = fp16(W[k][n]) for W1 (512x256), W2, W3 (256x256).
// ---------------------------------------------------------------------------
__global__ void prep_w_kernel(const float* __restrict__ W1, const float* __restrict__ W2,
                              const float* __restrict__ W3, __half* __restrict__ Wt1,
                              __half* __restrict__ Wt2, __half* __restrict__ Wt3)
{
  int gid = blockIdx.x * 256 + threadIdx.x;
  if (gid < 512 * 256) {
    int n = gid >> 9, k = gid & 511;
    Wt1[gid] = __float2half(W1[k * 256 + n]);
  } else if (gid < 512 * 256 + 256 * 256) {
    int g = gid - 512 * 256; int n = g >> 8, k = g & 255;
    Wt2[g] = __float2half(W2[k * 256 + n]);
  } else if (gid < 512 * 256 + 2 * 256 * 256) {
    int g = gid - 512 * 256 - 256 * 256; int n = g >> 8, k = g & 255;
    Wt3[g] = __float2half(W3[k * 256 + n]);
  }
}

// ---------------------------------------------------------------------------
// MFMA fp16 GEMM, 128x128 tiles, BK=64 (v2): 4 waves x (4x4 of 16x16x32 MFMA),
// two K-steps per barrier pair -> half the barrier/staging overhead of the
// BK=32 original.  K-accumulation order per acc element unchanged ->
// bit-identical outputs.  LDS 2x128x72x2B = 36 KB (72-half pitch = 36-dword
// stride -> same free 2-way bank aliasing as the verified 40-pad).
// ---------------------------------------------------------------------------
template<int MODE>
__global__ __launch_bounds__(256) void mfma_gemm_kernel(
    const float* __restrict__ Aq, const float* __restrict__ Ap_end,
    const float* __restrict__ Ap_start, const __half* __restrict__ Ah,
    const __half* __restrict__ Bh, const float* __restrict__ bias,
    __half* __restrict__ out)
{
  const int K = (MODE == 0) ? 512 : 256;
  const int M = (MODE == 3) ? NPTS : MROWS;
  __shared__ _Float16 As[128][72];
  __shared__ _Float16 Bs[128][72];
  const int t = threadIdx.x;
  const int lane = t & 63;
  const int wave = t >> 6;
  const int quad = lane >> 4, l15 = lane & 15;
  const int wm = wave & 1, wn = wave >> 1;
  const int m0 = blockIdx.x * 128;
  const int n0 = blockIdx.y * 128;
  const int b  = (MODE == 3) ? blockIdx.z : 0;
  const __half* F1 = Ah + (size_t)b * NPTS * 256;
  const __half* F2 = Ah + (size_t)(12000 + b * NPTS) * 256;

  f32x4 acc[4][4];
#pragma unroll
  for (int i = 0; i < 4; ++i)
#pragma unroll
    for (int j = 0; j < 4; ++j) acc[i][j] = (f32x4){0.f, 0.f, 0.f, 0.f};

  const int sr = t >> 1;            // staging row 0..127
  const int c0 = (t & 1) * 32;      // staging col offset {0,32}

  for (int kt = 0; kt < K; kt += 64) {
    // ---- stage A tile (128 x 64 halves; 32 halves/thread) ----
    {
      int grow = m0 + sr;
      if (MODE == 0) {
        union { half8 v[4]; _Float16 s[32]; } U;
        if (grow < M) {
          int col = kt + c0;              // 32-col block never straddles 256
          int r12 = (grow < 12000) ? grow : grow - 12000;
          const float* src;
          if (col < 256) src = Aq + (size_t)r12 * 256 + col;
          else src = ((grow < 12000) ? Ap_end : Ap_start) + (size_t)r12 * 256 + (col - 256);
#pragma unroll
          for (int i = 0; i < 8; ++i) {
            float4 w = ld4(src + 4 * i);
            U.s[4*i+0] = (_Float16)w.x; U.s[4*i+1] = (_Float16)w.y;
            U.s[4*i+2] = (_Float16)w.z; U.s[4*i+3] = (_Float16)w.w;
          }
        } else {
#pragma unroll
          for (int i = 0; i < 32; ++i) U.s[i] = (_Float16)0.f;
        }
#pragma unroll
        for (int i = 0; i < 4; ++i)
          *(half8*)&As[sr][c0 + 8 * i] = U.v[i];
      } else {
        const __half* src = ((MODE == 3) ? F1 : Ah) + (size_t)grow * 256 + kt + c0;
        uint4 u[4] = {make_uint4(0,0,0,0), make_uint4(0,0,0,0),
                      make_uint4(0,0,0,0), make_uint4(0,0,0,0)};
        if (grow < M) {
#pragma unroll
          for (int i = 0; i < 4; ++i) u[i] = *(const uint4*)(src + 8 * i);
        }
#pragma unroll
        for (int i = 0; i < 4; ++i)
          *(uint4*)&As[sr][c0 + 8 * i] = u[i];
      }
    }
    // ---- stage B tile (128 n-rows x 64 k) ----
    {
      int n = n0 + sr;
      uint4 u[4] = {make_uint4(0,0,0,0), make_uint4(0,0,0,0),
                    make_uint4(0,0,0,0), make_uint4(0,0,0,0)};
      if (MODE == 3) {
        if (n < NPTS) {
          const __half* src = F2 + (size_t)n * 256 + kt + c0;
#pragma unroll
          for (int i = 0; i < 4; ++i) u[i] = *(const uint4*)(src + 8 * i);
        }
      } else {
        const __half* src = Bh + (size_t)n * K + kt + c0;
#pragma unroll
        for (int i = 0; i < 4; ++i) u[i] = *(const uint4*)(src + 8 * i);
      }
#pragma unroll
      for (int i = 0; i < 4; ++i)
        *(uint4*)&Bs[sr][c0 + 8 * i] = u[i];
    }
    __syncthreads();
    // ---- MFMA: two K=32 steps per staged tile ----
#pragma unroll
    for (int step = 0; step < 2; ++step) {
      half8 af[4], bf[4];
#pragma unroll
      for (int sm = 0; sm < 4; ++sm)
        af[sm] = *(half8*)&As[wm * 64 + sm * 16 + l15][step * 32 + quad * 8];
#pragma unroll
      for (int sn = 0; sn < 4; ++sn)
        bf[sn] = *(half8*)&Bs[wn * 64 + sn * 16 + l15][step * 32 + quad * 8];
#pragma unroll
      for (int sm = 0; sm < 4; ++sm)
#pragma unroll
        for (int sn = 0; sn < 4; ++sn)
          acc[sm][sn] = __builtin_amdgcn_mfma_f32_16x16x32_f16(af[sm], bf[sn], acc[sm][sn], 0, 0, 0);
    }
    __syncthreads();
  }

  // ---- epilogue (unchanged) ----
  if (MODE == 3) {
    __half* Kb = out + (size_t)b * M1 * KH;
#pragma unroll
    for (int sm = 0; sm < 4; ++sm) {
      int rbase = m0 + wm * 64 + sm * 16 + quad * 4;
#pragma unroll
      for (int reg = 0; reg < 4; ++reg) {
        int gi = rbase + reg;
        if (gi < NPTS) {
#pragma unroll
          for (int sn = 0; sn < 4; ++sn) {
            int gj = n0 + wn * 64 + sn * 16 + l15;
            float v = acc[sm][sn][reg] * 0.0625f;
            float kv = (gj < NPTS && gj != gi) ? __expf(v) : 0.f;
            Kb[(size_t)gi * KH + gj] = __float2half(kv);
          }
        }
      }
    }
  } else {
    float bv[4];
#pragma unroll
    for (int sn = 0; sn < 4; ++sn) bv[sn] = bias[n0 + wn * 64 + sn * 16 + l15];
#pragma unroll
    for (int sm = 0; sm < 4; ++sm) {
      int rbase = m0 + wm * 64 + sm * 16 + quad * 4;
#pragma unroll
      for (int reg = 0; reg < 4; ++reg) {
        int gr = rbase + reg;
        if (gr < MROWS) {
#pragma unroll
          for (int sn = 0; sn < 4; ++sn) {
            int col = n0 + wn * 64 + sn * 16 + l15;
            float v = acc[sm][sn][reg] + bv[sn];
            if (MODE != 2) v = fmaxf(v, 0.f);
            out[(size_t)gr * 256 + col] = __float2half(v);
          }
        }
      }
    }
  }
}

// ---------------------------------------------------------------------------
// bins: bin row/col = fp16(exp(alpha)); zero bin-row pads; zero csum0.
// ---------------------------------------------------------------------------
__global__ void bins_kernel(__half* __restrict__ Kh, const float* __restrict__ palpha,
                            float* __restrict__ csum0)
{
  int gid = blockIdx.x * 256 + threadIdx.x;
  if (gid >= BATCH * KH) return;
  int b = gid / KH, x = gid % KH;
  __half He = __float2half(expf(palpha[0]));
  __half* Kb = Kh + (size_t)b * M1 * KH;
  csum0[gid] = 0.f;
  if (x < M1) {
    Kb[(size_t)NPTS * KH + x] = He;   // bin row
    Kb[(size_t)x * KH + NPTS] = He;   // bin col (corner included)
  } else {
    Kb[(size_t)NPTS * KH + x] = __float2half(0.f); // bin-row pads
  }
}

// ---------------------------------------------------------------------------
// Fused Sinkhorn iteration (fp16 K), ONE dispatch per iteration.
// (round-8 verified 646us version: 512 blocks, 256 thr, reg-resident ev,
// ALL 18 K-row loads issued up front, NT loads rows >= 1024, wpart combine)
// ---------------------------------------------------------------------------
#define PROCESS_ROW(UARR, I)                                                  \
  {                                                                           \
    float r[24], dot = 0.f;                                                   \
    _Pragma("unroll")                                                         \
    for (int k = 0; k < 3; ++k) {                                             \
      union { u32x4 u; __half2 h[4]; } U; U.u = UARR[k];                      \
      _Pragma("unroll")                                                       \
      for (int m = 0; m < 4; ++m) {                                           \
        float2 f = __half22float2(U.h[m]);                                    \
        r[k * 8 + 2 * m]     = f.x;                                           \
        r[k * 8 + 2 * m + 1] = f.y;                                           \
      }                                                                       \
      dot += r[k*8+0]*ev[k*8+0] + r[k*8+1]*ev[k*8+1] + r[k*8+2]*ev[k*8+2]     \
           + r[k*8+3]*ev[k*8+3] + r[k*8+4]*ev[k*8+4] + r[k*8+5]*ev[k*8+5]     \
           + r[k*8+6]*ev[k*8+6] + r[k*8+7]*ev[k*8+7];                         \
    }                                                                         \
    _Pragma("unroll")                                                         \
    for (int off = 32; off > 0; off >>= 1) dot += __shfl_xor(dot, off);       \
    float mu = ((I) < NPTS) ? MU_PT : MU_BIN;                                 \
    float euv = mu / dot;                                                     \
    if (wr_eu && lane == 0) eub[(I)] = euv;                                   \
    _Pragma("unroll")                                                         \
    for (int k = 0; k < 24; ++k) acc[k] += r[k] * euv;                        \
  }

__global__ __launch_bounds__(256) void sink_iter_kernel(
    const __half* __restrict__ Kh,
    const float* __restrict__ csum_prev,
    float* __restrict__ csum_cur,
    float* __restrict__ csum_zero,
    float* __restrict__ eu, int first, int wr_eu)
{
  const int t = threadIdx.x;
  const int wave = t >> 6, lane = t & 63;
  const int bb = blockIdx.x & 7;   // batch == XCD (heuristic, perf-only)
  const int rb = blockIdx.x >> 3;  // block-in-batch, 0..63
  const int wv = (rb << 2) | wave; // wave-in-batch, 0..255
  const __half* Kb = Kh + (size_t)bb * M1 * KH;
  float* eub = eu + bb * KH;

  __shared__ __align__(16) float wpart[4][KH];

  if (rb == 0) {
    for (int j = t; j < KH; j += 256) csum_zero[bb * KH + j] = 0.f;
  }

  // phase A: ev for this lane's 24 columns (lane*8+j + k*512), in registers
  float ev[24];
  if (first) {
#pragma unroll
    for (int k = 0; k < 3; ++k) {
      int cbase = (lane << 3) + (k << 9);
#pragma unroll
      for (int j = 0; j < 8; ++j) ev[k * 8 + j] = (cbase + j < M1) ? 1.0f : 0.f;
    }
  } else {
    const float* cp = csum_prev + bb * KH;
#pragma unroll
    for (int k = 0; k < 3; ++k) {
      int cbase = (lane << 3) + (k << 9);
      float4 a  = *(const float4*)(cp + cbase);
      float4 bq = *(const float4*)(cp + cbase + 4);
      float cs[8] = {a.x, a.y, a.z, a.w, bq.x, bq.y, bq.z, bq.w};
#pragma unroll
      for (int j = 0; j < 8; ++j) {
        int col = cbase + j;
        float nu = (col < NPTS) ? MU_PT : ((col == NPTS) ? MU_BIN : 0.f);
        ev[k * 8 + j] = (col < M1) ? (nu / cs[j]) : 0.f;
      }
    }
  }

  // phase B: this wave's 6 rows -- issue ALL 18 loads, then compute
  float acc[24];
#pragma unroll
  for (int k = 0; k < 24; ++k) acc[k] = 0.f;

  {
    const int i0 = wv,        i0b = wv + 256;
    const int i1 = wv + 512,  i1b = wv + 768;
    const int i2 = wv + 1024, i2b = wv + 1280;
    const bool has2b = (i2b < M1);         // wave-uniform (wv < 221)

    const __half* p0a = Kb + (size_t)i0  * KH;
    const __half* p0b = Kb + (size_t)i0b * KH;
    const __half* p1a = Kb + (size_t)i1  * KH;
    const __half* p1b = Kb + (size_t)i1b * KH;
    const __half* p2a = Kb + (size_t)i2  * KH;
    const __half* p2b = Kb + (size_t)(has2b ? i2b : i2) * KH;

    u32x4 A0[3], B0[3], A1[3], B1[3], A2[3], B2[3];
#pragma unroll
    for (int k = 0; k < 3; ++k) {
      const int o = (lane + (k << 6)) << 3;
      A0[k] = *(const u32x4*)(p0a + o);                                  // rows < 1024: pin in L2
      B0[k] = *(const u32x4*)(p0b + o);
      A1[k] = *(const u32x4*)(p1a + o);
      B1[k] = *(const u32x4*)(p1b + o);
      A2[k] = __builtin_nontemporal_load((const u32x4*)(p2a + o));       // rows >= 1024: NT
      B2[k] = __builtin_nontemporal_load((const u32x4*)(p2b + o));
    }

    PROCESS_ROW(A0, i0)
    PROCESS_ROW(B0, i0b)
    PROCESS_ROW(A1, i1)
    PROCESS_ROW(B1, i1b)
    PROCESS_ROW(A2, i2)
    if (has2b) PROCESS_ROW(B2, i2b)
  }

  // phase C: combine 4 waves in LDS, atomics into csum_cur
#pragma unroll
  for (int k = 0; k < 3; ++k) {
    int c = lane + (k << 6);
    float4 a0 = make_float4(acc[k*8+0], acc[k*8+1], acc[k*8+2], acc[k*8+3]);
    float4 a1 = make_float4(acc[k*8+4], acc[k*8+5], acc[k*8+6], acc[k*8+7]);
    *(float4*)&wpart[wave][(c << 3)]     = a0;
    *(float4*)&wpart[wave][(c << 3) + 4] = a1;
  }
  __syncthreads();
  for (int j = t; j < M1; j += 256) {
    float s = wpart[0][j] + wpart[1][j] + wpart[2][j] + wpart[3][j];
    atomicAdd(&csum_cur[bb * KH + j], s);
  }
}

// Final ev from last iteration's csum
__global__ void final_ev_kernel(const float* __restrict__ csum,
                                float* __restrict__ ev)
{
  int j = blockIdx.x * 256 + threadIdx.x;
  int bb = blockIdx.y;
  if (j >= M1) return;
  float nu = (j < NPTS) ? MU_PT : MU_BIN;
  ev[bb * KH + j] = nu / csum[bb * KH + j];
}

// out[b][i][j] = Kh * eu_i * ev_j * 3000.
// wave per output row, lane-strided (c = lane + k*64): every load/store
// instruction covers 64 consecutive elements (fully coalesced).
__global__ __launch_bounds__(256) void finalize_kernel(
    const __half* __restrict__ Kh, const float* __restrict__ eu,
    const float* __restrict__ ev, float* __restrict__ out)
{
  int rowid = blockIdx.x * 4 + (threadIdx.x >> 6);   // 0 .. BATCH*M1-1
  if (rowid >= BATCH * M1) return;
  int lane = threadIdx.x & 63;
  int b = rowid / M1, i = rowid % M1;
  const __half* krow = Kh + ((size_t)b * M1 + i) * KH;
  const float* evb = ev + b * KH;
  float* orow = out + (size_t)rowid * M1;
  float scale = eu[b * KH + i] * 3000.0f;
#pragma unroll
  for (int k = 0; k < 24; ++k) {
    int c = lane + (k << 6);
    if (c < M1)
      orow[c] = __half2float(krow[c]) * evb[c] * scale;
  }
}

// ---------------------------------------------------------------------------
extern "C" void kernel_launch(void* const* d_in, const int* in_sizes, int n_in,
                              void* d_out, int out_size, void* d_ws, size_t ws_size,
                              hipStream_t stream)
{
  const float* quer      = (const float*)d_in[0];
  const float* pos_start = (const float*)d_in[1];
  const float* pos_end   = (const float*)d_in[2];
  const float* W1 = (const float*)d_in[3];
  const float* b1 = (const float*)d_in[4];
  const float* W2 = (const float*)d_in[5];
  const float* b2 = (const float*)d_in[6];
  const float* W3 = (const float*)d_in[7];
  const float* b3 = (const float*)d_in[8];
  const float* alpha = (const float*)d_in[9];

  char* ws = (char*)d_ws;
  size_t off = 0;
  auto carve = [&](size_t bytes) -> void* {
    void* p = ws + off;
    off += (bytes + 1023) & ~(size_t)1023;
    return p;
  };
  __half* Ha  = (__half*)carve((size_t)MROWS * 256 * 2);          // 12.3 MB
  __half* Hb  = (__half*)carve((size_t)MROWS * 256 * 2);          // 12.3 MB
  __half* Kh  = (__half*)carve((size_t)BATCH * M1 * KH * 2);      // 36.9 MB
  __half* Wt1 = (__half*)carve((size_t)256 * 512 * 2);
  __half* Wt2 = (__half*)carve((size_t)256 * 256 * 2);
  __half* Wt3 = (__half*)carve((size_t)256 * 256 * 2);
  float* csum[3];
  for (int c = 0; c < 3; ++c) csum[c] = (float*)carve((size_t)BATCH * KH * 4);
  float* eu = (float*)carve((size_t)BATCH * KH * 4);
  float* ev = (float*)carve((size_t)BATCH * KH * 4);
  (void)ws_size; (void)in_sizes; (void)n_in; (void)out_size;

  dim3 blk(256);
  // weight prep (fp16, transposed to [n][k])
  prep_w_kernel<<<dim3(1024), blk, 0, stream>>>(W1, W2, W3, Wt1, Wt2, Wt3);
  // MLP via MFMA (BK=64): Ha = relu([q|p]W1+b1); Hb = relu(Ha W2+b2); Ha = Hb W3+b3
  mfma_gemm_kernel<0><<<dim3(188, 2), blk, 0, stream>>>(quer, pos_end, pos_start, nullptr, Wt1, b1, Ha);
  mfma_gemm_kernel<1><<<dim3(188, 2), blk, 0, stream>>>(nullptr, nullptr, nullptr, Ha, Wt2, b2, Hb);
  mfma_gemm_kernel<2><<<dim3(188, 2), blk, 0, stream>>>(nullptr, nullptr, nullptr, Hb, Wt3, b3, Ha);
  // scores -> Kh (fp16 exp domain, pads zeroed)
  mfma_gemm_kernel<3><<<dim3(12, 12, 8), blk, 0, stream>>>(nullptr, nullptr, nullptr, Ha, nullptr, nullptr, Kh);
  bins_kernel<<<dim3((BATCH * KH + 255) / 256), blk, 0, stream>>>(Kh, alpha, csum[0]);
  // sinkhorn: 50 fused dispatches, triple-buffered csum (round-8 verified engine)
  for (int it = 0; it < ITERS; ++it) {
    float* prev = csum[(it + 2) % 3];
    float* cur  = csum[it % 3];
    float* znxt = csum[(it + 1) % 3];
    sink_iter_kernel<<<dim3(512), blk, 0, stream>>>(Kh, prev, cur, znxt, eu,
                                                    it == 0 ? 1 : 0,
                                                    it == ITERS - 1 ? 1 : 0);
  }
  final_ev_kernel<<<dim3(6, 8), blk, 0, stream>>>(csum[(ITERS - 1) % 3], ev);
  // output (wave per row, coalesced)
  finalize_kernel<<<dim3((BATCH * M1 + 3) / 4), blk, 0, stream>>>(Kh, eu, ev, (float*)d_out);
}